// Round 3
// baseline (63.503 us; speedup 1.0000x reference)
//
#include <hip/hip_runtime.h>

// SAN subtraction2: K=7, S=1, P=3, D=1, reflect pad.
// N=8, C=64, H=W=56 -> out [8,64,49,3136] fp32.
// out[nc, kk=i*7+j, oh*56+ow] = in2[nc, refl(oh+i-3), refl(ow+j-3)] - in1[nc,oh,ow]
//
// Thread = (nc, i, oh, ow4): computes 7 j-outputs (7 float4 stores).
// R3 A/B: plain stores instead of __builtin_nontemporal_store (only change).

typedef float f4 __attribute__((ext_vector_type(4)));

#define KSZ 7
#define KK 49
#define HH 56
#define WW 56
#define L 3136   // 56*56
#define W4 14    // 56/4

__device__ __forceinline__ int refl56(int s) {
    // jnp reflect (no edge repeat): s<0 -> -s ; s>=56 -> 110-s
    s = s < 0 ? -s : s;
    return s >= 56 ? 110 - s : s;
}

__global__ __launch_bounds__(256) void sub2_kernel(
    const float* __restrict__ in1,
    const float* __restrict__ in2,
    float* __restrict__ out,
    int total)
{
    int tid = blockIdx.x * blockDim.x + threadIdx.x;
    if (tid >= total) return;

    // tid = (nc*7 + i)*784 + t,  t = oh*14 + ow4
    int t    = tid % 784;
    int rest = tid / 784;
    int i    = rest % KSZ;
    int nc   = rest / KSZ;

    int oh = t / W4;
    int ow = (t % W4) * 4;

    // query: one aligned float4 (read 7x total across i, hits L2/L3)
    const f4 q = *reinterpret_cast<const f4*>(in1 + (nc * HH + oh) * WW + ow);

    // key row for this i (vertical reflect picks a real row)
    int rh = refl56(oh + i - 3);
    const float* __restrict__ row = in2 + (nc * HH + rh) * WW;

    // 10-wide column window, horizontal reflect per column (branchless)
    float v[10];
#pragma unroll
    for (int d = 0; d < 10; ++d)
        v[d] = row[refl56(ow + d - 3)];

    // out base for kk = i*7 + 0
    float* outp = out + ((size_t)(nc * KK + i * KSZ) * L + oh * WW + ow);
#pragma unroll
    for (int j = 0; j < KSZ; ++j) {
        f4 r;
        r.x = v[j + 0] - q.x;
        r.y = v[j + 1] - q.y;
        r.z = v[j + 2] - q.z;
        r.w = v[j + 3] - q.w;
        *reinterpret_cast<f4*>(outp) = r;   // plain store (A/B vs nt)
        outp += L;
    }
}

extern "C" void kernel_launch(void* const* d_in, const int* in_sizes, int n_in,
                              void* d_out, int out_size, void* d_ws, size_t ws_size,
                              hipStream_t stream) {
    const float* in1 = (const float*)d_in[0];
    const float* in2 = (const float*)d_in[1];
    float* out = (float*)d_out;

    // threads = 512 nc * 7 i * 784 (oh,ow4) = 2,809,856
    int total = 512 * KSZ * 784;
    int block = 256;
    int grid = (total + block - 1) / block;
    sub2_kernel<<<grid, block, 0, stream>>>(in1, in2, out, total);
}